// Round 1
// baseline (259.505 us; speedup 1.0000x reference)
//
#include <hip/hip_runtime.h>

// TensorDense: e3nn-style CG tensor product, N=20000, MULT_IN=64, MID=16, OUT=64, l<=2.
// Fused design: per block = 16 samples.
//   Phase 0: a = x@W1/8, b = x@W2/8 into LDS (fp32).
//   Per path p (15 paths): z_p[(k,s), m=u*16+v] generated into LDS as bf16 in
//   MFMA-A fragment layout, then y += z_p @ W3_slice via mfma_f32_16x16x32_bf16.
//   W3 pre-packed to B-fragment order in d_ws (norm 1/sqrt(tp_mult) folded in).
// Hardcoded real-basis CG tables; each k-slice verified to have unit Frobenius norm.

typedef __attribute__((ext_vector_type(4))) float f32x4;
typedef __attribute__((ext_vector_type(8))) short short8;
typedef unsigned short ushort_t;
typedef unsigned int uint32;

__device__ __forceinline__ uint32 bfb(float x) {
  uint32 u = __float_as_uint(x);
  return (u + 0x7fffu + ((u >> 16) & 1u)) >> 16;  // RNE fp32->bf16
}
__device__ __forceinline__ uint32 pack2(float lo, float hi) {
  return bfb(lo) | (bfb(hi) << 16);
}

#define C2   0.7071067811865476f   // 1/sqrt(2)
#define C3   0.5773502691896258f   // 1/sqrt(3)
#define C5   0.4472135954999579f   // 1/sqrt(5)
#define C6   0.4082482904638631f   // 1/sqrt(6)
#define C23  0.8164965809277260f   // sqrt(2/3)
#define C10  0.3162277660168379f   // 1/sqrt(10)
#define C210 0.6324555320336759f   // 2/sqrt(10)
#define C310 0.5477225575051661f   // sqrt(3/10)
#define C14  0.2672612419124244f   // 1/sqrt(14)
#define C214 0.5345224838248488f   // 2/sqrt(14)
#define C314 0.4629100498862757f   // sqrt(3/14)

// ---------------- W3 pre-pack: B-fragment order, bf16, norm folded ----------------
// pack chunk index space: l0 chunks 0..23, l1 24..71, l2 72..119 (chunk = 32 K-rows)
// element layout: pack[((chunk*4 + wtile)*64 + lane)*8 + j] =
//   bf16( W3_l[m = chunk_m0 + (lane>>4)*8 + j][w = wtile*16 + (lane&15)] / sqrt(tp_mult_l) )
__global__ __launch_bounds__(256) void pack_w3_kernel(
    const float* __restrict__ W30, const float* __restrict__ W31,
    const float* __restrict__ W32, ushort_t* __restrict__ pack) {
  int lc = blockIdx.x;
  int t = threadIdx.x >> 6;
  int lam = threadIdx.x & 63;
  const float* W;
  int mb;
  float nrm;
  if (lc < 24) {
    W = W30; mb = lc * 32; nrm = 0.036084391824351615f;        // 1/sqrt(768)
  } else if (lc < 72) {
    W = W31; mb = (lc - 24) * 32; nrm = 0.025515518153991442f; // 1/sqrt(1536)
  } else {
    W = W32; mb = (lc - 72) * 32; nrm = 0.025515518153991442f;
  }
  int w = t * 16 + (lam & 15);
  int m0 = mb + (lam >> 4) * 8;
  ushort_t* dst = pack + ((size_t)(lc * 4 + t) * 64 + lam) * 8;
#pragma unroll
  for (int j = 0; j < 8; ++j)
    dst[j] = (ushort_t)bfb(W[(size_t)(m0 + j) * 64 + w] * nrm);
}

// ---------------- z generation helper ----------------
// thread (s,u) computes z[k][m=u*16+v] for v=0..15, writes rows of z_s.
// z_s layout: [k][s][264] ushort (bf16), row stride 264 (=256+8 pad for bank spread).
template <int NK, class F>
__device__ __forceinline__ void zgen_path(const float* bsrow, int boff, int s, int u,
                                          ushort_t* zs, F f) {
  uint32 zp[NK][8];
#pragma unroll
  for (int v2 = 0; v2 < 8; ++v2) {
    float z0[NK], z1[NK];
    f(bsrow + (2 * v2) * 12 + boff, z0);
    f(bsrow + (2 * v2 + 1) * 12 + boff, z1);
#pragma unroll
    for (int k = 0; k < NK; ++k) zp[k][v2] = pack2(z0[k], z1[k]);
  }
#pragma unroll
  for (int k = 0; k < NK; ++k) {
    uint32* dst = (uint32*)(zs + (k * 16 + s) * 264 + u * 16);
    *(uint4*)(dst) = make_uint4(zp[k][0], zp[k][1], zp[k][2], zp[k][3]);
    *(uint4*)(dst + 4) = make_uint4(zp[k][4], zp[k][5], zp[k][6], zp[k][7]);
  }
}

// ---------------- MFMA accumulate over one path's 8 K-chunks ----------------
// A-frag: lane holds z[row = rt*16 + (lane&15)][c*32 + (lane>>4)*8 + j]
// B-frag: pre-packed; D: col=lane&15 (w in tile), row=(lane>>4)*4+reg (sample s)
template <int NROW>
__device__ __forceinline__ void mfma_acc(const ushort_t* zs, const ushort_t* pack,
                                         int pcbase, int wt, int lane, f32x4* acc) {
  int srow = lane & 15, quad = lane >> 4;
  const ushort_t* ab = zs + srow * 264 + quad * 8;
  const ushort_t* bb = pack + ((size_t)(pcbase * 4 + wt) * 64 + lane) * 8;
#pragma unroll
  for (int c = 0; c < 8; ++c) {
    short8 B = *(const short8*)(bb + (size_t)c * 2048);
#pragma unroll
    for (int rt = 0; rt < NROW; ++rt) {
      short8 A = *(const short8*)(ab + rt * 16 * 264 + c * 32);
      acc[rt] = __builtin_amdgcn_mfma_f32_16x16x32_bf16(A, B, acc[rt], 0, 0, 0);
    }
  }
}

// ---------------- main fused kernel ----------------
__global__ __launch_bounds__(256) void tdense_kernel(
    const float* __restrict__ x0, const float* __restrict__ x1,
    const float* __restrict__ x2, const float* __restrict__ W10,
    const float* __restrict__ W20, const float* __restrict__ W11,
    const float* __restrict__ W21, const float* __restrict__ W12,
    const float* __restrict__ W22, const ushort_t* __restrict__ pack,
    float* __restrict__ out) {
  __shared__ float a_s[2304];                     // [s][v][9]
  __shared__ float b_s[3072];                     // [s][v][12] (padded)
  __shared__ __align__(16) ushort_t z_s[21120];   // [k<=5][s=16][264]

  const int tid = threadIdx.x;
  const int nbase = blockIdx.x * 16;

  // ---- Phase 0: branch linears a,b (fp32, /8 folded) ----
  for (int it = tid; it < 512; it += 256) {
    int brn = it >> 8;
    int s = (it >> 4) & 15;
    int v = it & 15;
    int n = nbase + s;
    const float* Wl0 = brn ? W20 : W10;
    const float* Wl1 = brn ? W21 : W11;
    const float* Wl2 = brn ? W22 : W12;
    const float* px0 = x0 + (size_t)n * 64;
    const float* px1 = x1 + (size_t)n * 192;
    const float* px2 = x2 + (size_t)n * 320;
    float s0 = 0.f, s1a = 0.f, s1b = 0.f, s1c = 0.f;
    float s2[5] = {0.f, 0.f, 0.f, 0.f, 0.f};
    for (int u = 0; u < 64; ++u) {
      float w0 = Wl0[u * 16 + v];
      float w1 = Wl1[u * 16 + v];
      float w2 = Wl2[u * 16 + v];
      s0 += px0[u] * w0;
      s1a += px1[u * 3 + 0] * w1;
      s1b += px1[u * 3 + 1] * w1;
      s1c += px1[u * 3 + 2] * w1;
#pragma unroll
      for (int j = 0; j < 5; ++j) s2[j] += px2[u * 5 + j] * w2;
    }
    float* dst = brn ? (b_s + (s * 16 + v) * 12) : (a_s + (s * 16 + v) * 9);
    dst[0] = s0 * 0.125f;
    dst[1] = s1a * 0.125f;
    dst[2] = s1b * 0.125f;
    dst[3] = s1c * 0.125f;
#pragma unroll
    for (int j = 0; j < 5; ++j) dst[4 + j] = s2[j] * 0.125f;
  }

  const int lane = tid & 63, wt = tid >> 6;
  const int zs_s = tid >> 4, zu = tid & 15;

  f32x4 acc0[1], acc1[3], acc2[5];
#pragma unroll
  for (int i = 0; i < 1; ++i) acc0[i] = (f32x4)(0.f);
#pragma unroll
  for (int i = 0; i < 3; ++i) acc1[i] = (f32x4)(0.f);
#pragma unroll
  for (int i = 0; i < 5; ++i) acc2[i] = (f32x4)(0.f);

  __syncthreads();

  float ar[9];
  {
    const float* arow = a_s + (zs_s * 16 + zu) * 9;
#pragma unroll
    for (int i = 0; i < 9; ++i) ar[i] = arow[i];
  }
  const float* bsrow = b_s + zs_s * 16 * 12;

#define RUN_PATH(NK, BOFF, PC, ACC, BODY)                         \
  zgen_path<NK>(bsrow, BOFF, zs_s, zu, z_s,                       \
                [&](const float* b, float* z) BODY);              \
  __syncthreads();                                                \
  mfma_acc<NK>(z_s, pack, PC, wt, lane, ACC);                     \
  __syncthreads();

  // p0 (0,0,0) -> l0 slot0
  RUN_PATH(1, 0, 0, acc0, { z[0] = ar[0] * b[0]; })
  // p1 (0,1,1) -> l1 slot0
  RUN_PATH(3, 1, 24, acc1, {
    z[0] = ar[0] * b[0]; z[1] = ar[0] * b[1]; z[2] = ar[0] * b[2];
  })
  // p2 (0,2,2) -> l2 slot0
  RUN_PATH(5, 4, 72, acc2, {
    z[0] = ar[0] * b[0]; z[1] = ar[0] * b[1]; z[2] = ar[0] * b[2];
    z[3] = ar[0] * b[3]; z[4] = ar[0] * b[4];
  })
  // p3 (1,0,1) -> l1 slot1
  RUN_PATH(3, 0, 32, acc1, {
    z[0] = ar[1] * b[0]; z[1] = ar[2] * b[0]; z[2] = ar[3] * b[0];
  })
  // p4 (1,1,0) -> l0 slot1
  RUN_PATH(1, 1, 8, acc0, {
    z[0] = -C3 * (ar[1] * b[0] + ar[2] * b[1] + ar[3] * b[2]);
  })
  // p5 (1,1,1) -> l1 slot2 (cross product / sqrt2)
  RUN_PATH(3, 1, 40, acc1, {
    z[0] = C2 * (ar[2] * b[2] - ar[3] * b[1]);
    z[1] = C2 * (ar[3] * b[0] - ar[1] * b[2]);
    z[2] = C2 * (ar[1] * b[1] - ar[2] * b[0]);
  })
  // p6 (1,1,2) -> l2 slot1
  RUN_PATH(5, 1, 80, acc2, {
    z[0] = C2 * (ar[1] * b[2] + ar[3] * b[0]);
    z[1] = C2 * (ar[2] * b[0] + ar[1] * b[1]);
    z[2] = C23 * ar[2] * b[1] - C6 * (ar[1] * b[0] + ar[3] * b[2]);
    z[3] = C2 * (ar[2] * b[2] + ar[3] * b[1]);
    z[4] = C2 * (ar[3] * b[2] - ar[1] * b[0]);
  })
  // p7 (1,2,1) -> l1 slot3
  RUN_PATH(3, 4, 48, acc1, {
    z[0] = -C310 * ar[2] * b[1] + C10 * ar[1] * b[2] - C310 * ar[3] * b[0] + C310 * ar[1] * b[4];
    z[1] = -C210 * ar[2] * b[2] - C310 * ar[3] * b[3] - C310 * ar[1] * b[1];
    z[2] = -C310 * ar[2] * b[3] + C10 * ar[3] * b[2] - C310 * ar[1] * b[0] - C310 * ar[3] * b[4];
  })
  // p8 (1,2,2) -> l2 slot2
  RUN_PATH(5, 4, 88, acc2, {
    z[0] = C23 * ar[2] * b[4] + C6 * ar[1] * b[1] - C6 * ar[3] * b[3];
    z[1] = C6 * ar[2] * b[3] - C6 * ar[1] * b[0] - C2 * ar[3] * b[2] - C6 * ar[3] * b[4];
    z[2] = C2 * (ar[3] * b[1] - ar[1] * b[3]);
    z[3] = -C6 * ar[2] * b[1] + C2 * ar[1] * b[2] + C6 * ar[3] * b[0] - C6 * ar[1] * b[4];
    z[4] = -C23 * ar[2] * b[0] + C6 * ar[1] * b[3] + C6 * ar[3] * b[1];
  })
  // p9 (2,0,2) -> l2 slot3
  RUN_PATH(5, 0, 96, acc2, {
    z[0] = ar[4] * b[0]; z[1] = ar[5] * b[0]; z[2] = ar[6] * b[0];
    z[3] = ar[7] * b[0]; z[4] = ar[8] * b[0];
  })
  // p10 (2,1,1) -> l1 slot4
  RUN_PATH(3, 1, 56, acc1, {
    z[0] = -C310 * ar[5] * b[1] + C10 * ar[6] * b[0] - C310 * ar[4] * b[2] + C310 * ar[8] * b[0];
    z[1] = -C210 * ar[6] * b[1] - C310 * ar[7] * b[2] - C310 * ar[5] * b[0];
    z[2] = -C310 * ar[7] * b[1] + C10 * ar[6] * b[2] - C310 * ar[4] * b[0] - C310 * ar[8] * b[2];
  })
  // p11 (2,1,2) -> l2 slot4
  RUN_PATH(5, 1, 104, acc2, {
    z[0] = -C23 * ar[8] * b[1] - C6 * ar[5] * b[0] + C6 * ar[7] * b[2];
    z[1] = -C6 * ar[7] * b[1] + C6 * ar[4] * b[0] + C2 * ar[6] * b[2] + C6 * ar[8] * b[2];
    z[2] = C2 * (ar[7] * b[0] - ar[5] * b[2]);
    z[3] = C6 * ar[5] * b[1] - C2 * ar[6] * b[0] - C6 * ar[4] * b[2] + C6 * ar[8] * b[0];
    z[4] = C23 * ar[4] * b[1] - C6 * ar[7] * b[0] - C6 * ar[5] * b[2];
  })
  // p12 (2,2,0) -> l0 slot2
  RUN_PATH(1, 4, 16, acc0, {
    z[0] = C5 * (ar[4] * b[0] + ar[5] * b[1] + ar[6] * b[2] + ar[7] * b[3] + ar[8] * b[4]);
  })
  // p13 (2,2,1) -> l1 slot5
  RUN_PATH(3, 4, 64, acc1, {
    z[0] = C10 * (ar[8] * b[3] - ar[7] * b[4] + ar[4] * b[1] - ar[5] * b[0]) +
           C310 * (ar[7] * b[2] - ar[6] * b[3]);
    z[1] = C10 * (ar[5] * b[3] - ar[7] * b[1]) + C210 * (ar[4] * b[4] - ar[8] * b[0]);
    z[2] = C10 * (ar[8] * b[1] - ar[5] * b[4] + ar[7] * b[0] - ar[4] * b[3]) +
           C310 * (ar[6] * b[1] - ar[5] * b[2]);
  })
  // p14 (2,2,2) -> l2 slot5
  RUN_PATH(5, 4, 112, acc2, {
    z[0] = C214 * (ar[6] * b[0] + ar[4] * b[2]) - C314 * (ar[5] * b[3] + ar[7] * b[1]);
    z[1] = -C14 * (ar[6] * b[1] + ar[5] * b[2]) + C314 * (ar[5] * b[4] + ar[8] * b[1]) -
           C314 * (ar[7] * b[0] + ar[4] * b[3]);
    z[2] = -C214 * ar[6] * b[2] - C14 * (ar[5] * b[1] + ar[7] * b[3]) +
           C214 * (ar[4] * b[0] + ar[8] * b[4]);
    z[3] = -C14 * (ar[6] * b[3] + ar[7] * b[2]) - C314 * (ar[5] * b[0] + ar[4] * b[1]) -
           C314 * (ar[7] * b[4] + ar[8] * b[3]);
    z[4] = C214 * (ar[6] * b[4] + ar[8] * b[2]) + C314 * (ar[5] * b[1] - ar[7] * b[3]);
  })
#undef RUN_PATH

  // ---- Epilogue: D layout col=lane&15 (w), row=(lane>>4)*4+reg (s) ----
  {
    const int col = lane & 15, quad = lane >> 4;
    const int w = wt * 16 + col;
#pragma unroll
    for (int r = 0; r < 4; ++r) {
      int s = quad * 4 + r;
      float* row = out + (size_t)(nbase + s) * 576;
      row[w] = acc0[0][r];
      row[64 + w * 3 + 0] = acc1[0][r];
      row[64 + w * 3 + 1] = acc1[1][r];
      row[64 + w * 3 + 2] = acc1[2][r];
#pragma unroll
      for (int k = 0; k < 5; ++k) row[256 + w * 5 + k] = acc2[k][r];
    }
  }
}

extern "C" void kernel_launch(void* const* d_in, const int* in_sizes, int n_in,
                              void* d_out, int out_size, void* d_ws, size_t ws_size,
                              hipStream_t stream) {
  const float* x0 = (const float*)d_in[0];
  const float* x1 = (const float*)d_in[1];
  const float* x2 = (const float*)d_in[2];
  const float* W10 = (const float*)d_in[3];
  const float* W20 = (const float*)d_in[4];
  const float* W11 = (const float*)d_in[5];
  const float* W21 = (const float*)d_in[6];
  const float* W12 = (const float*)d_in[7];
  const float* W22 = (const float*)d_in[8];
  const float* W30 = (const float*)d_in[9];
  const float* W31 = (const float*)d_in[10];
  const float* W32 = (const float*)d_in[11];
  ushort_t* pack = (ushort_t*)d_ws;  // 491,520 bytes used

  hipLaunchKernelGGL(pack_w3_kernel, dim3(120), dim3(256), 0, stream,
                     W30, W31, W32, pack);

  int nsamp = in_sizes[0] / 64;  // 20000
  int nblocks = nsamp / 16;      // 1250
  hipLaunchKernelGGL(tdense_kernel, dim3(nblocks), dim3(256), 0, stream,
                     x0, x1, x2, W10, W20, W11, W21, W12, W22, pack,
                     (float*)d_out);
}

// Round 2
// 222.739 us; speedup vs baseline: 1.1651x; 1.1651x over previous
//
#include <hip/hip_runtime.h>

// TensorDense: e3nn CG tensor product, N=20000, MULT_IN=64, MID=16, OUT=64, l<=2.
// R2: merged branch linears (a kept in registers), transposed+padded b_s,
// float2 packed-pair zgen with v_perm bf16 pack, float4 x loads, 10 barrier rounds.

typedef __attribute__((ext_vector_type(4))) float f32x4;
typedef __attribute__((ext_vector_type(4))) float f4;
typedef __attribute__((ext_vector_type(2))) float f2;
typedef __attribute__((ext_vector_type(8))) short short8;
typedef unsigned short ushort_t;
typedef unsigned int uint32;

__device__ __forceinline__ uint32 bfb(float x) {
  uint32 u = __float_as_uint(x);
  return (u + 0x7fffu + ((u >> 16) & 1u)) >> 16;  // RNE fp32->bf16 (pack kernel only)
}

// cheap round-half-away pack of 2 fp32 -> packed bf16x2: 2 adds + 1 v_perm
__device__ __forceinline__ uint32 pack2f(f2 z) {
  uint32 lo = __float_as_uint(z.x) + 0x8000u;
  uint32 hi = __float_as_uint(z.y) + 0x8000u;
  return __builtin_amdgcn_perm(hi, lo, 0x07060302u);
}

#define C2   0.7071067811865476f
#define C3   0.5773502691896258f
#define C5   0.4472135954999579f
#define C6   0.4082482904638631f
#define C23  0.8164965809277260f
#define C10  0.3162277660168379f
#define C210 0.6324555320336759f
#define C310 0.5477225575051661f
#define C14  0.2672612419124244f
#define C214 0.5345224838248488f
#define C314 0.4629100498862757f

// ---------------- W3 pre-pack (unchanged from R1) ----------------
__global__ __launch_bounds__(256) void pack_w3_kernel(
    const float* __restrict__ W30, const float* __restrict__ W31,
    const float* __restrict__ W32, ushort_t* __restrict__ pack) {
  int lc = blockIdx.x;
  int t = threadIdx.x >> 6;
  int lam = threadIdx.x & 63;
  const float* W;
  int mb;
  float nrm;
  if (lc < 24) {
    W = W30; mb = lc * 32; nrm = 0.036084391824351615f;        // 1/sqrt(768)
  } else if (lc < 72) {
    W = W31; mb = (lc - 24) * 32; nrm = 0.025515518153991442f; // 1/sqrt(1536)
  } else {
    W = W32; mb = (lc - 72) * 32; nrm = 0.025515518153991442f;
  }
  int w = t * 16 + (lam & 15);
  int m0 = mb + (lam >> 4) * 8;
  ushort_t* dst = pack + ((size_t)(lc * 4 + t) * 64 + lam) * 8;
#pragma unroll
  for (int j = 0; j < 8; ++j)
    dst[j] = (ushort_t)bfb(W[(size_t)(m0 + j) * 64 + w] * nrm);
}

// ---------------- z generation: float2 pairs, vector b reads ----------------
// b_s layout: [s][jg][v] floats, s-stride 148 (148%32=20 -> conflict-free broadcasts)
// bsj points at the path's j-block base (b_s + s*148 + {0,16,64}).
// zrow = z_s + (kbase*16 + s)*264 + u*16  (ushorts); writes NK rows of 16 bf16.
template <int NK, int JD, class F>
__device__ __forceinline__ void zgenv(const float* bsj, ushort_t* zrow, F f) {
  uint32 zp[NK][8];
#pragma unroll
  for (int oc = 0; oc < 2; ++oc) {
    f2 bb4[JD][4];
#pragma unroll
    for (int j = 0; j < JD; ++j) {
      f4 lo = *(const f4*)(bsj + j * 16 + oc * 8);
      f4 hi = *(const f4*)(bsj + j * 16 + oc * 8 + 4);
      bb4[j][0] = lo.xy; bb4[j][1] = lo.zw;
      bb4[j][2] = hi.xy; bb4[j][3] = hi.zw;
    }
#pragma unroll
    for (int q = 0; q < 4; ++q) {
      f2 bcol[JD], z[NK];
#pragma unroll
      for (int j = 0; j < JD; ++j) bcol[j] = bb4[j][q];
      f(bcol, z);
#pragma unroll
      for (int k = 0; k < NK; ++k) zp[k][oc * 4 + q] = pack2f(z[k]);
    }
  }
#pragma unroll
  for (int k = 0; k < NK; ++k) {
    uint32* d = (uint32*)(zrow + k * (16 * 264));
    *(uint4*)(d) = make_uint4(zp[k][0], zp[k][1], zp[k][2], zp[k][3]);
    *(uint4*)(d + 4) = make_uint4(zp[k][4], zp[k][5], zp[k][6], zp[k][7]);
  }
}

// ---------------- MFMA accumulate: one path, NROW k-tiles from kbase ----------------
template <int NROW>
__device__ __forceinline__ void mfma_acc(const ushort_t* zs, const ushort_t* pack,
                                         int kbase, int pcbase, int wt, int lane,
                                         f32x4* acc) {
  int srow = lane & 15, quad = lane >> 4;
  const ushort_t* ab = zs + (kbase * 16 + srow) * 264 + quad * 8;
  const ushort_t* bb = pack + ((size_t)(pcbase * 4 + wt) * 64 + lane) * 8;
#pragma unroll
  for (int c = 0; c < 8; ++c) {
    short8 B = *(const short8*)(bb + (size_t)c * 2048);
#pragma unroll
    for (int rt = 0; rt < NROW; ++rt) {
      short8 A = *(const short8*)(ab + rt * (16 * 264) + c * 32);
      acc[rt] = __builtin_amdgcn_mfma_f32_16x16x32_bf16(A, B, acc[rt], 0, 0, 0);
    }
  }
}

// ---------------- main fused kernel ----------------
__global__ __launch_bounds__(256, 2) void tdense_kernel(
    const float* __restrict__ x0, const float* __restrict__ x1,
    const float* __restrict__ x2, const float* __restrict__ W10,
    const float* __restrict__ W20, const float* __restrict__ W11,
    const float* __restrict__ W21, const float* __restrict__ W12,
    const float* __restrict__ W22, const ushort_t* __restrict__ pack,
    float* __restrict__ out) {
  __shared__ float b_s[2368];                    // [s][9 j-slots][16 v], stride 148
  __shared__ __align__(16) ushort_t z_s[25344];  // 6 k-rows x 16 s x 264

  const int tid = threadIdx.x;
  const int nbase = blockIdx.x * 16;
  const int s = tid >> 4, v = tid & 15;

  // ---- Phase 0: both branch linears in one pass; a stays in registers ----
  const int n = nbase + s;
  const float* px0 = x0 + (size_t)n * 64;
  const float* px1 = x1 + (size_t)n * 192;
  const float* px2 = x2 + (size_t)n * 320;
  float a0 = 0.f, a1x = 0.f, a1y = 0.f, a1z = 0.f;
  float a2[5] = {0.f, 0.f, 0.f, 0.f, 0.f};
  float b0 = 0.f, b1x = 0.f, b1y = 0.f, b1z = 0.f;
  float b2[5] = {0.f, 0.f, 0.f, 0.f, 0.f};
  for (int u4 = 0; u4 < 16; ++u4) {
    f4 xv0 = *(const f4*)(px0 + u4 * 4);
    f4 xa = *(const f4*)(px1 + u4 * 12);
    f4 xb = *(const f4*)(px1 + u4 * 12 + 4);
    f4 xc = *(const f4*)(px1 + u4 * 12 + 8);
    f4 ya = *(const f4*)(px2 + u4 * 20);
    f4 yb = *(const f4*)(px2 + u4 * 20 + 4);
    f4 yc = *(const f4*)(px2 + u4 * 20 + 8);
    f4 yd = *(const f4*)(px2 + u4 * 20 + 12);
    f4 ye = *(const f4*)(px2 + u4 * 20 + 16);
    float x1e[12], x2e[20];
#pragma unroll
    for (int e = 0; e < 4; ++e) { x1e[e] = xa[e]; x1e[4 + e] = xb[e]; x1e[8 + e] = xc[e]; }
#pragma unroll
    for (int e = 0; e < 4; ++e) {
      x2e[e] = ya[e]; x2e[4 + e] = yb[e]; x2e[8 + e] = yc[e];
      x2e[12 + e] = yd[e]; x2e[16 + e] = ye[e];
    }
#pragma unroll
    for (int r = 0; r < 4; ++r) {
      int u = u4 * 4 + r;
      float wa0 = W10[u * 16 + v], wb0 = W20[u * 16 + v];
      float wa1 = W11[u * 16 + v], wb1 = W21[u * 16 + v];
      float wa2 = W12[u * 16 + v], wb2 = W22[u * 16 + v];
      float xx = xv0[r];
      a0 += xx * wa0; b0 += xx * wb0;
      float e0 = x1e[r * 3 + 0], e1 = x1e[r * 3 + 1], e2 = x1e[r * 3 + 2];
      a1x += e0 * wa1; a1y += e1 * wa1; a1z += e2 * wa1;
      b1x += e0 * wb1; b1y += e1 * wb1; b1z += e2 * wb1;
#pragma unroll
      for (int j = 0; j < 5; ++j) {
        float ev = x2e[r * 5 + j];
        a2[j] += ev * wa2;
        b2[j] += ev * wb2;
      }
    }
  }
  const float inv8 = 0.125f;
  float ar[9];
  ar[0] = a0 * inv8;
  ar[1] = a1x * inv8; ar[2] = a1y * inv8; ar[3] = a1z * inv8;
#pragma unroll
  for (int j = 0; j < 5; ++j) ar[4 + j] = a2[j] * inv8;
  {
    float* bw = b_s + s * 148 + v;
    bw[0] = b0 * inv8;
    bw[16] = b1x * inv8; bw[32] = b1y * inv8; bw[48] = b1z * inv8;
#pragma unroll
    for (int j = 0; j < 5; ++j) bw[64 + j * 16] = b2[j] * inv8;
  }

  const int lane = tid & 63, wt = tid >> 6;
  f32x4 acc0[1], acc1[3], acc2[5];
  acc0[0] = (f32x4)(0.f);
#pragma unroll
  for (int i = 0; i < 3; ++i) acc1[i] = (f32x4)(0.f);
#pragma unroll
  for (int i = 0; i < 5; ++i) acc2[i] = (f32x4)(0.f);

  __syncthreads();

  const float* bsl0 = b_s + s * 148;       // l0 j-block
  const float* bsl1 = b_s + s * 148 + 16;  // l1 j-block
  const float* bsl2 = b_s + s * 148 + 64;  // l2 j-block
  ushort_t* zr0 = z_s + s * 264 + v * 16;  // kbase=0 row base for this thread
#define ZROW(kb) (zr0 + (kb) * (16 * 264))

  // ---- R0: p0(000) kb0 pc0; p4(110) kb1 pc8; p12(220) kb2 pc16; p1(011) kb3 pc24 ----
  zgenv<1, 1>(bsl0, ZROW(0), [&](const f2* b, f2* z) { z[0] = ar[0] * b[0]; });
  zgenv<1, 3>(bsl1, ZROW(1), [&](const f2* b, f2* z) {
    z[0] = -C3 * (ar[1] * b[0] + ar[2] * b[1] + ar[3] * b[2]);
  });
  zgenv<1, 5>(bsl2, ZROW(2), [&](const f2* b, f2* z) {
    z[0] = C5 * (ar[4] * b[0] + ar[5] * b[1] + ar[6] * b[2] + ar[7] * b[3] + ar[8] * b[4]);
  });
  zgenv<3, 3>(bsl1, ZROW(3), [&](const f2* b, f2* z) {
    z[0] = ar[0] * b[0]; z[1] = ar[0] * b[1]; z[2] = ar[0] * b[2];
  });
  __syncthreads();
  mfma_acc<1>(z_s, pack, 0, 0, wt, lane, acc0);
  mfma_acc<1>(z_s, pack, 1, 8, wt, lane, acc0);
  mfma_acc<1>(z_s, pack, 2, 16, wt, lane, acc0);
  mfma_acc<3>(z_s, pack, 3, 24, wt, lane, acc1);
  __syncthreads();

  // ---- R1: p3(101) kb0 pc32; p5(111) kb3 pc40 ----
  zgenv<3, 1>(bsl0, ZROW(0), [&](const f2* b, f2* z) {
    z[0] = ar[1] * b[0]; z[1] = ar[2] * b[0]; z[2] = ar[3] * b[0];
  });
  zgenv<3, 3>(bsl1, ZROW(3), [&](const f2* b, f2* z) {
    z[0] = C2 * (ar[2] * b[2] - ar[3] * b[1]);
    z[1] = C2 * (ar[3] * b[0] - ar[1] * b[2]);
    z[2] = C2 * (ar[1] * b[1] - ar[2] * b[0]);
  });
  __syncthreads();
  mfma_acc<3>(z_s, pack, 0, 32, wt, lane, acc1);
  mfma_acc<3>(z_s, pack, 3, 40, wt, lane, acc1);
  __syncthreads();

  // ---- R2: p7(121) kb0 pc48; p10(211) kb3 pc56 ----
  zgenv<3, 5>(bsl2, ZROW(0), [&](const f2* b, f2* z) {
    z[0] = -C310 * ar[2] * b[1] + C10 * ar[1] * b[2] - C310 * ar[3] * b[0] + C310 * ar[1] * b[4];
    z[1] = -C210 * ar[2] * b[2] - C310 * ar[3] * b[3] - C310 * ar[1] * b[1];
    z[2] = -C310 * ar[2] * b[3] + C10 * ar[3] * b[2] - C310 * ar[1] * b[0] - C310 * ar[3] * b[4];
  });
  zgenv<3, 3>(bsl1, ZROW(3), [&](const f2* b, f2* z) {
    z[0] = -C310 * ar[5] * b[1] + C10 * ar[6] * b[0] - C310 * ar[4] * b[2] + C310 * ar[8] * b[0];
    z[1] = -C210 * ar[6] * b[1] - C310 * ar[7] * b[2] - C310 * ar[5] * b[0];
    z[2] = -C310 * ar[7] * b[1] + C10 * ar[6] * b[2] - C310 * ar[4] * b[0] - C310 * ar[8] * b[2];
  });
  __syncthreads();
  mfma_acc<3>(z_s, pack, 0, 48, wt, lane, acc1);
  mfma_acc<3>(z_s, pack, 3, 56, wt, lane, acc1);
  __syncthreads();

  // ---- R3: p13(221) kb0 pc64 ----
  zgenv<3, 5>(bsl2, ZROW(0), [&](const f2* b, f2* z) {
    z[0] = C10 * (ar[8] * b[3] - ar[7] * b[4] + ar[4] * b[1] - ar[5] * b[0]) +
           C310 * (ar[7] * b[2] - ar[6] * b[3]);
    z[1] = C10 * (ar[5] * b[3] - ar[7] * b[1]) + C210 * (ar[4] * b[4] - ar[8] * b[0]);
    z[2] = C10 * (ar[8] * b[1] - ar[5] * b[4] + ar[7] * b[0] - ar[4] * b[3]) +
           C310 * (ar[6] * b[1] - ar[5] * b[2]);
  });
  __syncthreads();
  mfma_acc<3>(z_s, pack, 0, 64, wt, lane, acc1);
  __syncthreads();

  // ---- R4: p2(022) kb0 pc72 ----
  zgenv<5, 5>(bsl2, ZROW(0), [&](const f2* b, f2* z) {
    z[0] = ar[0] * b[0]; z[1] = ar[0] * b[1]; z[2] = ar[0] * b[2];
    z[3] = ar[0] * b[3]; z[4] = ar[0] * b[4];
  });
  __syncthreads();
  mfma_acc<5>(z_s, pack, 0, 72, wt, lane, acc2);
  __syncthreads();

  // ---- R5: p6(112) kb0 pc80 ----
  zgenv<5, 3>(bsl1, ZROW(0), [&](const f2* b, f2* z) {
    z[0] = C2 * (ar[1] * b[2] + ar[3] * b[0]);
    z[1] = C2 * (ar[2] * b[0] + ar[1] * b[1]);
    z[2] = C23 * ar[2] * b[1] - C6 * (ar[1] * b[0] + ar[3] * b[2]);
    z[3] = C2 * (ar[2] * b[2] + ar[3] * b[1]);
    z[4] = C2 * (ar[3] * b[2] - ar[1] * b[0]);
  });
  __syncthreads();
  mfma_acc<5>(z_s, pack, 0, 80, wt, lane, acc2);
  __syncthreads();

  // ---- R6: p8(122) kb0 pc88 ----
  zgenv<5, 5>(bsl2, ZROW(0), [&](const f2* b, f2* z) {
    z[0] = C23 * ar[2] * b[4] + C6 * ar[1] * b[1] - C6 * ar[3] * b[3];
    z[1] = C6 * ar[2] * b[3] - C6 * ar[1] * b[0] - C2 * ar[3] * b[2] - C6 * ar[3] * b[4];
    z[2] = C2 * (ar[3] * b[1] - ar[1] * b[3]);
    z[3] = -C6 * ar[2] * b[1] + C2 * ar[1] * b[2] + C6 * ar[3] * b[0] - C6 * ar[1] * b[4];
    z[4] = -C23 * ar[2] * b[0] + C6 * ar[1] * b[3] + C6 * ar[3] * b[1];
  });
  __syncthreads();
  mfma_acc<5>(z_s, pack, 0, 88, wt, lane, acc2);
  __syncthreads();

  // ---- R7: p9(202) kb0 pc96 ----
  zgenv<5, 1>(bsl0, ZROW(0), [&](const f2* b, f2* z) {
    z[0] = ar[4] * b[0]; z[1] = ar[5] * b[0]; z[2] = ar[6] * b[0];
    z[3] = ar[7] * b[0]; z[4] = ar[8] * b[0];
  });
  __syncthreads();
  mfma_acc<5>(z_s, pack, 0, 96, wt, lane, acc2);
  __syncthreads();

  // ---- R8: p11(212) kb0 pc104 ----
  zgenv<5, 3>(bsl1, ZROW(0), [&](const f2* b, f2* z) {
    z[0] = -C23 * ar[8] * b[1] - C6 * ar[5] * b[0] + C6 * ar[7] * b[2];
    z[1] = -C6 * ar[7] * b[1] + C6 * ar[4] * b[0] + C2 * ar[6] * b[2] + C6 * ar[8] * b[2];
    z[2] = C2 * (ar[7] * b[0] - ar[5] * b[2]);
    z[3] = C6 * ar[5] * b[1] - C2 * ar[6] * b[0] - C6 * ar[4] * b[2] + C6 * ar[8] * b[0];
    z[4] = C23 * ar[4] * b[1] - C6 * ar[7] * b[0] - C6 * ar[5] * b[2];
  });
  __syncthreads();
  mfma_acc<5>(z_s, pack, 0, 104, wt, lane, acc2);
  __syncthreads();

  // ---- R9: p14(222) kb0 pc112 ----
  zgenv<5, 5>(bsl2, ZROW(0), [&](const f2* b, f2* z) {
    z[0] = C214 * (ar[6] * b[0] + ar[4] * b[2]) - C314 * (ar[5] * b[3] + ar[7] * b[1]);
    z[1] = -C14 * (ar[6] * b[1] + ar[5] * b[2]) + C314 * (ar[5] * b[4] + ar[8] * b[1]) -
           C314 * (ar[7] * b[0] + ar[4] * b[3]);
    z[2] = -C214 * ar[6] * b[2] - C14 * (ar[5] * b[1] + ar[7] * b[3]) +
           C214 * (ar[4] * b[0] + ar[8] * b[4]);
    z[3] = -C14 * (ar[6] * b[3] + ar[7] * b[2]) - C314 * (ar[5] * b[0] + ar[4] * b[1]) -
           C314 * (ar[7] * b[4] + ar[8] * b[3]);
    z[4] = C214 * (ar[6] * b[4] + ar[8] * b[2]) + C314 * (ar[5] * b[1] - ar[7] * b[3]);
  });
  __syncthreads();
  mfma_acc<5>(z_s, pack, 0, 112, wt, lane, acc2);
#undef ZROW

  // ---- Epilogue: D layout col=lane&15 (w in tile), row=(lane>>4)*4+reg (s) ----
  {
    const int col = lane & 15, quad = lane >> 4;
    const int w = wt * 16 + col;
#pragma unroll
    for (int r = 0; r < 4; ++r) {
      int so = quad * 4 + r;
      float* row = out + (size_t)(nbase + so) * 576;
      row[w] = acc0[0][r];
      row[64 + w * 3 + 0] = acc1[0][r];
      row[64 + w * 3 + 1] = acc1[1][r];
      row[64 + w * 3 + 2] = acc1[2][r];
#pragma unroll
      for (int k = 0; k < 5; ++k) row[256 + w * 5 + k] = acc2[k][r];
    }
  }
}

extern "C" void kernel_launch(void* const* d_in, const int* in_sizes, int n_in,
                              void* d_out, int out_size, void* d_ws, size_t ws_size,
                              hipStream_t stream) {
  const float* x0 = (const float*)d_in[0];
  const float* x1 = (const float*)d_in[1];
  const float* x2 = (const float*)d_in[2];
  const float* W10 = (const float*)d_in[3];
  const float* W20 = (const float*)d_in[4];
  const float* W11 = (const float*)d_in[5];
  const float* W21 = (const float*)d_in[6];
  const float* W12 = (const float*)d_in[7];
  const float* W22 = (const float*)d_in[8];
  const float* W30 = (const float*)d_in[9];
  const float* W31 = (const float*)d_in[10];
  const float* W32 = (const float*)d_in[11];
  ushort_t* pack = (ushort_t*)d_ws;  // 491,520 bytes used

  hipLaunchKernelGGL(pack_w3_kernel, dim3(120), dim3(256), 0, stream,
                     W30, W31, W32, pack);

  int nsamp = in_sizes[0] / 64;  // 20000
  int nblocks = nsamp / 16;      // 1250
  hipLaunchKernelGGL(tdense_kernel, dim3(nblocks), dim3(256), 0, stream,
                     x0, x1, x2, W10, W20, W11, W21, W12, W22, pack,
                     (float*)d_out);
}

// Round 3
// 218.939 us; speedup vs baseline: 1.1853x; 1.0174x over previous
//
#include <hip/hip_runtime.h>

// TensorDense: e3nn CG tensor product, N=20000, MULT_IN=64, MID=16, OUT=64, l<=2.
// R3: K-split x w-pair wave tiling (each wave: 2 w-tiles x 4 of 8 K-chunks ->
// A-frag LDS reads halved, 2 MFMAs per A read), ping-pong z buffers with ONE
// barrier per round (19 rounds; NK5 paths split 3+2 rows) so zgen VALU, LDS
// A-reads and MFMA co-issue. Cross-wave (h=0/h=1) accumulator reduction via LDS.

typedef __attribute__((ext_vector_type(4))) float f32x4;
typedef __attribute__((ext_vector_type(4))) float f4;
typedef __attribute__((ext_vector_type(2))) float f2;
typedef __attribute__((ext_vector_type(8))) short short8;
typedef unsigned short ushort_t;
typedef unsigned int uint32;

__device__ __forceinline__ uint32 bfb(float x) {
  uint32 u = __float_as_uint(x);
  return (u + 0x7fffu + ((u >> 16) & 1u)) >> 16;  // RNE fp32->bf16 (pack kernel)
}
// round-half-away pack of 2 fp32 -> packed bf16x2: 2 adds + 1 v_perm
__device__ __forceinline__ uint32 pack2f(f2 z) {
  uint32 lo = __float_as_uint(z.x) + 0x8000u;
  uint32 hi = __float_as_uint(z.y) + 0x8000u;
  return __builtin_amdgcn_perm(hi, lo, 0x07060302u);
}

#define C2   0.7071067811865476f
#define C3   0.5773502691896258f
#define C5   0.4472135954999579f
#define C6   0.4082482904638631f
#define C23  0.8164965809277260f
#define C10  0.3162277660168379f
#define C210 0.6324555320336759f
#define C310 0.5477225575051661f
#define C14  0.2672612419124244f
#define C214 0.5345224838248488f
#define C314 0.4629100498862757f

// ---------------- W3 pre-pack: B-fragment order, bf16, norm folded ----------------
__global__ __launch_bounds__(256) void pack_w3_kernel(
    const float* __restrict__ W30, const float* __restrict__ W31,
    const float* __restrict__ W32, ushort_t* __restrict__ pack) {
  int lc = blockIdx.x;
  int t = threadIdx.x >> 6;
  int lam = threadIdx.x & 63;
  const float* W;
  int mb;
  float nrm;
  if (lc < 24) {
    W = W30; mb = lc * 32; nrm = 0.036084391824351615f;        // 1/sqrt(768)
  } else if (lc < 72) {
    W = W31; mb = (lc - 24) * 32; nrm = 0.025515518153991442f; // 1/sqrt(1536)
  } else {
    W = W32; mb = (lc - 72) * 32; nrm = 0.025515518153991442f;
  }
  int w = t * 16 + (lam & 15);
  int m0 = mb + (lam >> 4) * 8;
  ushort_t* dst = pack + ((size_t)(lc * 4 + t) * 64 + lam) * 8;
#pragma unroll
  for (int j = 0; j < 8; ++j)
    dst[j] = (ushort_t)bfb(W[(size_t)(m0 + j) * 64 + w] * nrm);
}

// ---------------- z generation (unchanged from R2) ----------------
// b_s: [s][9 jslots][16 v] floats, s-stride 148 (20 mod 32 -> conflict-free bcast)
template <int NK, int JD, class F>
__device__ __forceinline__ void zgenv(const float* bsj, ushort_t* zrow, F f) {
  uint32 zp[NK][8];
#pragma unroll
  for (int oc = 0; oc < 2; ++oc) {
    f2 bb4[JD][4];
#pragma unroll
    for (int j = 0; j < JD; ++j) {
      f4 lo = *(const f4*)(bsj + j * 16 + oc * 8);
      f4 hi = *(const f4*)(bsj + j * 16 + oc * 8 + 4);
      bb4[j][0] = lo.xy; bb4[j][1] = lo.zw;
      bb4[j][2] = hi.xy; bb4[j][3] = hi.zw;
    }
#pragma unroll
    for (int q = 0; q < 4; ++q) {
      f2 bcol[JD], z[NK];
#pragma unroll
      for (int j = 0; j < JD; ++j) bcol[j] = bb4[j][q];
      f(bcol, z);
#pragma unroll
      for (int k = 0; k < NK; ++k) zp[k][oc * 4 + q] = pack2f(z[k]);
    }
  }
#pragma unroll
  for (int k = 0; k < NK; ++k) {
    uint32* d = (uint32*)(zrow + k * (16 * 264));
    *(uint4*)(d) = make_uint4(zp[k][0], zp[k][1], zp[k][2], zp[k][3]);
    *(uint4*)(d + 4) = make_uint4(zp[k][4], zp[k][5], zp[k][6], zp[k][7]);
  }
}

// ---------------- MFMA: NROW k-rows, this wave's 4 K-chunks, 2 w-tiles ----------------
// B depends only on (path, chunk, wt): reused across the NROW k-rows.
template <int NROW>
__device__ __forceinline__ void mfma2(const ushort_t* zb, const ushort_t* pk,
                                      int pcbase, int h, int wt0, int lane,
                                      f32x4* accA, f32x4* accB) {
  const int srow = lane & 15, quad = lane >> 4;
  const ushort_t* ab = zb + srow * 264 + quad * 8 + h * 128;  // chunk base h*4 -> +128 ushorts
  const ushort_t* bb = pk + ((size_t)((pcbase + h * 4) * 4 + wt0) * 64 + lane) * 8;
#pragma unroll
  for (int c = 0; c < 4; ++c) {
    short8 B0 = *(const short8*)(bb + (size_t)c * 2048);
    short8 B1 = *(const short8*)(bb + (size_t)c * 2048 + 512);
#pragma unroll
    for (int rt = 0; rt < NROW; ++rt) {
      short8 A = *(const short8*)(ab + rt * (16 * 264) + c * 32);
      accA[rt] = __builtin_amdgcn_mfma_f32_16x16x32_bf16(A, B0, accA[rt], 0, 0, 0);
      accB[rt] = __builtin_amdgcn_mfma_f32_16x16x32_bf16(A, B1, accB[rt], 0, 0, 0);
    }
  }
}

#define ZB 12672  // one ping-pong buffer: 3 slots x 16 rows x 264 ushorts

// ---------------- main fused kernel ----------------
__global__ __launch_bounds__(256, 2) void tdense_kernel(
    const float* __restrict__ x0, const float* __restrict__ x1,
    const float* __restrict__ x2, const float* __restrict__ W10,
    const float* __restrict__ W20, const float* __restrict__ W11,
    const float* __restrict__ W21, const float* __restrict__ W12,
    const float* __restrict__ W22, const ushort_t* __restrict__ pack,
    float* __restrict__ out) {
  __shared__ float b_s[2368];                        // 9.25 KB
  __shared__ __align__(16) ushort_t zbuf[2 * ZB];    // 50.7 KB (2 buffers x 3 slots)

  const int tid = threadIdx.x;
  const int nbase = blockIdx.x * 16;
  const int s = tid >> 4, v = tid & 15;

  // ---- Phase 0: both branch linears; a stays in registers (wave-local b_s) ----
  const int n = nbase + s;
  const float* px0 = x0 + (size_t)n * 64;
  const float* px1 = x1 + (size_t)n * 192;
  const float* px2 = x2 + (size_t)n * 320;
  float a0 = 0.f, a1x = 0.f, a1y = 0.f, a1z = 0.f;
  float a2[5] = {0.f, 0.f, 0.f, 0.f, 0.f};
  float b0 = 0.f, b1x = 0.f, b1y = 0.f, b1z = 0.f;
  float b2[5] = {0.f, 0.f, 0.f, 0.f, 0.f};
  for (int u4 = 0; u4 < 16; ++u4) {
    f4 xv0 = *(const f4*)(px0 + u4 * 4);
    f4 xa = *(const f4*)(px1 + u4 * 12);
    f4 xb = *(const f4*)(px1 + u4 * 12 + 4);
    f4 xc = *(const f4*)(px1 + u4 * 12 + 8);
    f4 ya = *(const f4*)(px2 + u4 * 20);
    f4 yb = *(const f4*)(px2 + u4 * 20 + 4);
    f4 yc = *(const f4*)(px2 + u4 * 20 + 8);
    f4 yd = *(const f4*)(px2 + u4 * 20 + 12);
    f4 ye = *(const f4*)(px2 + u4 * 20 + 16);
    float x1e[12], x2e[20];
#pragma unroll
    for (int e = 0; e < 4; ++e) { x1e[e] = xa[e]; x1e[4 + e] = xb[e]; x1e[8 + e] = xc[e]; }
#pragma unroll
    for (int e = 0; e < 4; ++e) {
      x2e[e] = ya[e]; x2e[4 + e] = yb[e]; x2e[8 + e] = yc[e];
      x2e[12 + e] = yd[e]; x2e[16 + e] = ye[e];
    }
#pragma unroll
    for (int r = 0; r < 4; ++r) {
      int u = u4 * 4 + r;
      float wa0 = W10[u * 16 + v], wb0 = W20[u * 16 + v];
      float wa1 = W11[u * 16 + v], wb1 = W21[u * 16 + v];
      float wa2 = W12[u * 16 + v], wb2 = W22[u * 16 + v];
      float xx = xv0[r];
      a0 += xx * wa0; b0 += xx * wb0;
      float e0 = x1e[r * 3 + 0], e1 = x1e[r * 3 + 1], e2 = x1e[r * 3 + 2];
      a1x += e0 * wa1; a1y += e1 * wa1; a1z += e2 * wa1;
      b1x += e0 * wb1; b1y += e1 * wb1; b1z += e2 * wb1;
#pragma unroll
      for (int j = 0; j < 5; ++j) {
        float ev = x2e[r * 5 + j];
        a2[j] += ev * wa2;
        b2[j] += ev * wb2;
      }
    }
  }
  const float inv8 = 0.125f;
  float ar[9];
  ar[0] = a0 * inv8;
  ar[1] = a1x * inv8; ar[2] = a1y * inv8; ar[3] = a1z * inv8;
#pragma unroll
  for (int j = 0; j < 5; ++j) ar[4 + j] = a2[j] * inv8;
  {
    float* bw = b_s + s * 148 + v;
    bw[0] = b0 * inv8;
    bw[16] = b1x * inv8; bw[32] = b1y * inv8; bw[48] = b1z * inv8;
#pragma unroll
    for (int j = 0; j < 5; ++j) bw[64 + j * 16] = b2[j] * inv8;
  }

  const int lane = tid & 63;
  const int wv = tid >> 6;
  const int p2 = (wv & 1) * 2;  // wt0: wave's first w-tile
  const int h = wv >> 1;        // K-half: chunks h*4..h*4+3

  f32x4 aA0, aB0, aA1[3], aB1[3], aA2[5], aB2[5];
  aA0 = (f32x4)(0.f); aB0 = (f32x4)(0.f);
#pragma unroll
  for (int i = 0; i < 3; ++i) { aA1[i] = (f32x4)(0.f); aB1[i] = (f32x4)(0.f); }
#pragma unroll
  for (int i = 0; i < 5; ++i) { aA2[i] = (f32x4)(0.f); aB2[i] = (f32x4)(0.f); }

  const float* bsl0 = b_s + s * 148;
  const float* bsl1 = bsl0 + 16;
  const float* bsl2 = bsl0 + 64;
  ushort_t* z0 = zbuf + s * 264 + v * 16;  // buf0, slot0 row for this thread
  ushort_t* z1 = z0 + ZB;                  // buf1
  const ushort_t* Zb0 = zbuf;
  const ushort_t* Zb1 = zbuf + ZB;

  // ---- R0 zgen -> buf0: p0(000)@slot0/pc0, p4(110)@slot1/pc8, p12(220)@slot2/pc16
  zgenv<1, 1>(bsl0, z0, [&](const f2* b, f2* z) { z[0] = ar[0] * b[0]; });
  zgenv<1, 3>(bsl1, z0 + 4224, [&](const f2* b, f2* z) {
    z[0] = -C3 * (ar[1] * b[0] + ar[2] * b[1] + ar[3] * b[2]);
  });
  zgenv<1, 5>(bsl2, z0 + 8448, [&](const f2* b, f2* z) {
    z[0] = C5 * (ar[4] * b[0] + ar[5] * b[1] + ar[6] * b[2] + ar[7] * b[3] + ar[8] * b[4]);
  });
  __syncthreads();

  // r=0: zgen R1 (p1(011) NK3) -> buf1 ; mfma R0 (buf0, acc0)
  zgenv<3, 3>(bsl1, z1, [&](const f2* b, f2* z) {
    z[0] = ar[0] * b[0]; z[1] = ar[0] * b[1]; z[2] = ar[0] * b[2];
  });
  mfma2<1>(Zb0, pack, 0, h, p2, lane, &aA0, &aB0);
  mfma2<1>(Zb0 + 4224, pack, 8, h, p2, lane, &aA0, &aB0);
  mfma2<1>(Zb0 + 8448, pack, 16, h, p2, lane, &aA0, &aB0);
  __syncthreads();

  // r=1: zgen R2 (p3(101)) -> buf0 ; mfma R1 (buf1, pc24, acc1)
  zgenv<3, 1>(bsl0, z0, [&](const f2* b, f2* z) {
    z[0] = ar[1] * b[0]; z[1] = ar[2] * b[0]; z[2] = ar[3] * b[0];
  });
  mfma2<3>(Zb1, pack, 24, h, p2, lane, aA1, aB1);
  __syncthreads();

  // r=2: zgen R3 (p5(111)) -> buf1 ; mfma R2 (buf0, pc32)
  zgenv<3, 3>(bsl1, z1, [&](const f2* b, f2* z) {
    z[0] = C2 * (ar[2] * b[2] - ar[3] * b[1]);
    z[1] = C2 * (ar[3] * b[0] - ar[1] * b[2]);
    z[2] = C2 * (ar[1] * b[1] - ar[2] * b[0]);
  });
  mfma2<3>(Zb0, pack, 32, h, p2, lane, aA1, aB1);
  __syncthreads();

  // r=3: zgen R4 (p7(121)) -> buf0 ; mfma R3 (buf1, pc40)
  zgenv<3, 5>(bsl2, z0, [&](const f2* b, f2* z) {
    z[0] = -C310 * ar[2] * b[1] + C10 * ar[1] * b[2] - C310 * ar[3] * b[0] + C310 * ar[1] * b[4];
    z[1] = -C210 * ar[2] * b[2] - C310 * ar[3] * b[3] - C310 * ar[1] * b[1];
    z[2] = -C310 * ar[2] * b[3] + C10 * ar[3] * b[2] - C310 * ar[1] * b[0] - C310 * ar[3] * b[4];
  });
  mfma2<3>(Zb1, pack, 40, h, p2, lane, aA1, aB1);
  __syncthreads();

  // r=4: zgen R5 (p10(211)) -> buf1 ; mfma R4 (buf0, pc48)
  zgenv<3, 3>(bsl1, z1, [&](const f2* b, f2* z) {
    z[0] = -C310 * ar[5] * b[1] + C10 * ar[6] * b[0] - C310 * ar[4] * b[2] + C310 * ar[8] * b[0];
    z[1] = -C210 * ar[6] * b[1] - C310 * ar[7] * b[2] - C310 * ar[5] * b[0];
    z[2] = -C310 * ar[7] * b[1] + C10 * ar[6] * b[2] - C310 * ar[4] * b[0] - C310 * ar[8] * b[2];
  });
  mfma2<3>(Zb0, pack, 48, h, p2, lane, aA1, aB1);
  __syncthreads();

  // r=5: zgen R6 (p13(221)) -> buf0 ; mfma R5 (buf1, pc56)
  zgenv<3, 5>(bsl2, z0, [&](const f2* b, f2* z) {
    z[0] = C10 * (ar[8] * b[3] - ar[7] * b[4] + ar[4] * b[1] - ar[5] * b[0]) +
           C310 * (ar[7] * b[2] - ar[6] * b[3]);
    z[1] = C10 * (ar[5] * b[3] - ar[7] * b[1]) + C210 * (ar[4] * b[4] - ar[8] * b[0]);
    z[2] = C10 * (ar[8] * b[1] - ar[5] * b[4] + ar[7] * b[0] - ar[4] * b[3]) +
           C310 * (ar[6] * b[1] - ar[5] * b[2]);
  });
  mfma2<3>(Zb1, pack, 56, h, p2, lane, aA1, aB1);
  __syncthreads();

  // r=6: zgen R7 (p2(022) rows 0-2) -> buf1 ; mfma R6 (buf0, pc64)
  zgenv<3, 5>(bsl2, z1, [&](const f2* b, f2* z) {
    z[0] = ar[0] * b[0]; z[1] = ar[0] * b[1]; z[2] = ar[0] * b[2];
  });
  mfma2<3>(Zb0, pack, 64, h, p2, lane, aA1, aB1);
  __syncthreads();

  // r=7: zgen R8 (p2 rows 3-4) -> buf0 ; mfma R7 (buf1, pc72, acc2[0..2])
  zgenv<2, 5>(bsl2, z0, [&](const f2* b, f2* z) {
    z[0] = ar[0] * b[3]; z[1] = ar[0] * b[4];
  });
  mfma2<3>(Zb1, pack, 72, h, p2, lane, aA2, aB2);
  __syncthreads();

  // r=8: zgen R9 (p6(112) rows 0-2) -> buf1 ; mfma R8 (buf0, pc72, acc2[3..4])
  zgenv<3, 3>(bsl1, z1, [&](const f2* b, f2* z) {
    z[0] = C2 * (ar[1] * b[2] + ar[3] * b[0]);
    z[1] = C2 * (ar[2] * b[0] + ar[1] * b[1]);
    z[2] = C23 * ar[2] * b[1] - C6 * (ar[1] * b[0] + ar[3] * b[2]);
  });
  mfma2<2>(Zb0, pack, 72, h, p2, lane, aA2 + 3, aB2 + 3);
  __syncthreads();

  // r=9: zgen R10 (p6 rows 3-4) -> buf0 ; mfma R9 (buf1, pc80, acc2[0..2])
  zgenv<2, 3>(bsl1, z0, [&](const f2* b, f2* z) {
    z[0] = C2 * (ar[2] * b[2] + ar[3] * b[1]);
    z[1] = C2 * (ar[3] * b[2] - ar[1] * b[0]);
  });
  mfma2<3>(Zb1, pack, 80, h, p2, lane, aA2, aB2);
  __syncthreads();

  // r=10: zgen R11 (p8(122) rows 0-2) -> buf1 ; mfma R10 (buf0, pc80, acc2[3..4])
  zgenv<3, 5>(bsl2, z1, [&](const f2* b, f2* z) {
    z[0] = C23 * ar[2] * b[4] + C6 * ar[1] * b[1] - C6 * ar[3] * b[3];
    z[1] = C6 * ar[2] * b[3] - C6 * ar[1] * b[0] - C2 * ar[3] * b[2] - C6 * ar[3] * b[4];
    z[2] = C2 * (ar[3] * b[1] - ar[1] * b[3]);
  });
  mfma2<2>(Zb0, pack, 80, h, p2, lane, aA2 + 3, aB2 + 3);
  __syncthreads();

  // r=11: zgen R12 (p8 rows 3-4) -> buf0 ; mfma R11 (buf1, pc88, acc2[0..2])
  zgenv<2, 5>(bsl2, z0, [&](const f2* b, f2* z) {
    z[0] = -C6 * ar[2] * b[1] + C2 * ar[1] * b[2] + C6 * ar[3] * b[0] - C6 * ar[1] * b[4];
    z[1] = -C23 * ar[2] * b[0] + C6 * ar[1] * b[3] + C6 * ar[3] * b[1];
  });
  mfma2<3>(Zb1, pack, 88, h, p2, lane, aA2, aB2);
  __syncthreads();

  // r=12: zgen R13 (p9(202) rows 0-2) -> buf1 ; mfma R12 (buf0, pc88, acc2[3..4])
  zgenv<3, 1>(bsl0, z1, [&](const f2* b, f2* z) {
    z[0] = ar[4] * b[0]; z[1] = ar[5] * b[0]; z[2] = ar[6] * b[0];
  });
  mfma2<2>(Zb0, pack, 88, h, p2, lane, aA2 + 3, aB2 + 3);
  __syncthreads();

  // r=13: zgen R14 (p9 rows 3-4) -> buf0 ; mfma R13 (buf1, pc96, acc2[0..2])
  zgenv<2, 1>(bsl0, z0, [&](const f2* b, f2* z) {
    z[0] = ar[7] * b[0]; z[1] = ar[8] * b[0];
  });
  mfma2<3>(Zb1, pack, 96, h, p2, lane, aA2, aB2);
  __syncthreads();

  // r=14: zgen R15 (p11(212) rows 0-2) -> buf1 ; mfma R14 (buf0, pc96, acc2[3..4])
  zgenv<3, 3>(bsl1, z1, [&](const f2* b, f2* z) {
    z[0] = -C23 * ar[8] * b[1] - C6 * ar[5] * b[0] + C6 * ar[7] * b[2];
    z[1] = -C6 * ar[7] * b[1] + C6 * ar[4] * b[0] + C2 * ar[6] * b[2] + C6 * ar[8] * b[2];
    z[2] = C2 * (ar[7] * b[0] - ar[5] * b[2]);
  });
  mfma2<2>(Zb0, pack, 96, h, p2, lane, aA2 + 3, aB2 + 3);
  __syncthreads();

  // r=15: zgen R16 (p11 rows 3-4) -> buf0 ; mfma R15 (buf1, pc104, acc2[0..2])
  zgenv<2, 3>(bsl1, z0, [&](const f2* b, f2* z) {
    z[0] = C6 * ar[5] * b[1] - C2 * ar[6] * b[0] - C6 * ar[4] * b[2] + C6 * ar[8] * b[0];
    z[1] = C23 * ar[4] * b[1] - C6 * ar[7] * b[0] - C6 * ar[5] * b[2];
  });
  mfma2<3>(Zb1, pack, 104, h, p2, lane, aA2, aB2);
  __syncthreads();

  // r=16: zgen R17 (p14(222) rows 0-2) -> buf1 ; mfma R16 (buf0, pc104, acc2[3..4])
  zgenv<3, 5>(bsl2, z1, [&](const f2* b, f2* z) {
    z[0] = C214 * (ar[6] * b[0] + ar[4] * b[2]) - C314 * (ar[5] * b[3] + ar[7] * b[1]);
    z[1] = -C14 * (ar[6] * b[1] + ar[5] * b[2]) + C314 * (ar[5] * b[4] + ar[8] * b[1]) -
           C314 * (ar[7] * b[0] + ar[4] * b[3]);
    z[2] = -C214 * ar[6] * b[2] - C14 * (ar[5] * b[1] + ar[7] * b[3]) +
           C214 * (ar[4] * b[0] + ar[8] * b[4]);
  });
  mfma2<2>(Zb0, pack, 104, h, p2, lane, aA2 + 3, aB2 + 3);
  __syncthreads();

  // r=17: zgen R18 (p14 rows 3-4) -> buf0 ; mfma R17 (buf1, pc112, acc2[0..2])
  zgenv<2, 5>(bsl2, z0, [&](const f2* b, f2* z) {
    z[0] = -C14 * (ar[6] * b[3] + ar[7] * b[2]) - C314 * (ar[5] * b[0] + ar[4] * b[1]) -
           C314 * (ar[7] * b[4] + ar[8] * b[3]);
    z[1] = C214 * (ar[6] * b[4] + ar[8] * b[2]) + C314 * (ar[5] * b[1] - ar[7] * b[3]);
  });
  mfma2<3>(Zb1, pack, 112, h, p2, lane, aA2, aB2);
  __syncthreads();

  // r=18: mfma R18 (buf0, pc112, acc2[3..4])
  mfma2<2>(Zb0, pack, 112, h, p2, lane, aA2 + 3, aB2 + 3);
  __syncthreads();  // all reads of zbuf done before reduction overwrites it

  // ---- Cross-wave K-half reduction via LDS, then global store (h==1 waves) ----
  float* red = (float*)zbuf;  // needs 36864 floats*4B? no: 9216 f32 per wt*... 36.9KB <= 50.7KB
  const int col = lane & 15, quad = lane >> 4;
  if (h == 0) {
#pragma unroll
    for (int pp = 0; pp < 2; ++pp) {
      int wt = p2 + pp;
      const f32x4* src0 = pp ? &aB0 : &aA0;
      const f32x4* src1 = pp ? aB1 : aA1;
      const f32x4* src2 = pp ? aB2 : aA2;
      *(f4*)(red + (wt * 9 + 0) * 256 + lane * 4) = src0[0];
#pragma unroll
      for (int o = 0; o < 3; ++o)
        *(f4*)(red + (wt * 9 + 1 + o) * 256 + lane * 4) = src1[o];
#pragma unroll
      for (int o = 0; o < 5; ++o)
        *(f4*)(red + (wt * 9 + 4 + o) * 256 + lane * 4) = src2[o];
    }
  }
  __syncthreads();
  if (h == 1) {
    aA0 += *(const f4*)(red + (p2 * 9 + 0) * 256 + lane * 4);
    aB0 += *(const f4*)(red + ((p2 + 1) * 9 + 0) * 256 + lane * 4);
#pragma unroll
    for (int o = 0; o < 3; ++o) {
      aA1[o] += *(const f4*)(red + (p2 * 9 + 1 + o) * 256 + lane * 4);
      aB1[o] += *(const f4*)(red + ((p2 + 1) * 9 + 1 + o) * 256 + lane * 4);
    }
#pragma unroll
    for (int o = 0; o < 5; ++o) {
      aA2[o] += *(const f4*)(red + (p2 * 9 + 4 + o) * 256 + lane * 4);
      aB2[o] += *(const f4*)(red + ((p2 + 1) * 9 + 4 + o) * 256 + lane * 4);
    }
    const int w0 = p2 * 16 + col, w1 = w0 + 16;
#pragma unroll
    for (int r = 0; r < 4; ++r) {
      int so = quad * 4 + r;
      float* row = out + (size_t)(nbase + so) * 576;
      row[w0] = aA0[r];
      row[w1] = aB0[r];
      row[64 + w0 * 3 + 0] = aA1[0][r];
      row[64 + w0 * 3 + 1] = aA1[1][r];
      row[64 + w0 * 3 + 2] = aA1[2][r];
      row[64 + w1 * 3 + 0] = aB1[0][r];
      row[64 + w1 * 3 + 1] = aB1[1][r];
      row[64 + w1 * 3 + 2] = aB1[2][r];
#pragma unroll
      for (int k = 0; k < 5; ++k) {
        row[256 + w0 * 5 + k] = aA2[k][r];
        row[256 + w1 * 5 + k] = aB2[k][r];
      }
    }
  }
}

extern "C" void kernel_launch(void* const* d_in, const int* in_sizes, int n_in,
                              void* d_out, int out_size, void* d_ws, size_t ws_size,
                              hipStream_t stream) {
  const float* x0 = (const float*)d_in[0];
  const float* x1 = (const float*)d_in[1];
  const float* x2 = (const float*)d_in[2];
  const float* W10 = (const float*)d_in[3];
  const float* W20 = (const float*)d_in[4];
  const float* W11 = (const float*)d_in[5];
  const float* W21 = (const float*)d_in[6];
  const float* W12 = (const float*)d_in[7];
  const float* W22 = (const float*)d_in[8];
  const float* W30 = (const float*)d_in[9];
  const float* W31 = (const float*)d_in[10];
  const float* W32 = (const float*)d_in[11];
  ushort_t* pack = (ushort_t*)d_ws;  // 491,520 bytes used

  hipLaunchKernelGGL(pack_w3_kernel, dim3(120), dim3(256), 0, stream,
                     W30, W31, W32, pack);

  int nsamp = in_sizes[0] / 64;  // 20000
  int nblocks = nsamp / 16;      // 1250
  hipLaunchKernelGGL(tdense_kernel, dim3(nblocks), dim3(256), 0, stream,
                     x0, x1, x2, W10, W20, W11, W21, W12, W22, pack,
                     (float*)d_out);
}